// Round 1
// 1426.886 us; speedup vs baseline: 1.1338x; 1.1338x over previous
//
#include <hip/hip_runtime.h>

// BitNet MLP: out = (silu(x@Gw^T * gs) * (x@Uw^T * us)) @ Dw^T * ds
// M=4096 tokens, K=4096 hidden, I=11008 inter. Ternary weights -> exact in bf16.
//
// R7: pipeline rebuild. Both GEMMs move from the 2-barrier 128^2 structure
// (m97-class, 886 TF, MfmaUtil 38.7%) to a 256^2-tile, 8-wave, BK=32,
// 4-deep-LDS pipeline with counted s_waitcnt vmcnt(8) once per K-tile
// (never 0 in the main loop), raw s_barrier (no compiler vmcnt drain),
// s_setprio(1) around MFMA clusters, bijective XCD block remap.
// gate/up weights are interleaved at 16-row granularity by the convert
// kernel so gemm1 stays a plain 2-stream GEMM; SwiGLU pairs adjacent
// 16-col fragments in the epilogue. LDS swizzle unchanged (conflict-free,
// verified SQ_LDS_BANK_CONFLICT==0 in R6).

typedef short short8 __attribute__((ext_vector_type(8)));
typedef float f32x4 __attribute__((ext_vector_type(4)));
typedef float fvec4 __attribute__((ext_vector_type(4)));
typedef unsigned short usvec4 __attribute__((ext_vector_type(4)));

__device__ __forceinline__ unsigned short f2bf(float f) {
    unsigned int u = __float_as_uint(f);
    u += 0x7FFFu + ((u >> 16) & 1u);   // round-to-nearest-even
    return (unsigned short)(u >> 16);
}

__global__ void cvt_f32_bf16(const fvec4* __restrict__ src,
                             usvec4* __restrict__ dst, long n4) {
    long i = (long)blockIdx.x * blockDim.x + threadIdx.x;
    if (i < n4) {
        fvec4 v = __builtin_nontemporal_load(src + i);
        usvec4 o;
        o.x = f2bf(v.x); o.y = f2bf(v.y); o.z = f2bf(v.z); o.w = f2bf(v.w);
        dst[i] = o;
    }
}

// Convert gate+up and interleave at 16-row granularity into one combined
// weight matrix: combined rows [32b..32b+16) = gate rows [16b..16b+16),
// combined rows [32b+16..32b+32) = up rows. Kh/4 == 1024 vec4 per row.
__global__ void cvt2_f32_bf16_ilv(const fvec4* __restrict__ s0,
                                  const fvec4* __restrict__ s1,
                                  usvec4* __restrict__ d, long n4) {
    long i = (long)blockIdx.x * blockDim.x + threadIdx.x;
    if (i < n4) {
        long j = i >> 10;          // local inter row
        long c = i & 1023;
        long Rg = ((j & ~15L) << 1) | (j & 15);
        fvec4 a = __builtin_nontemporal_load(s0 + i);
        fvec4 b = __builtin_nontemporal_load(s1 + i);
        usvec4 oa, ob;
        oa.x = f2bf(a.x); oa.y = f2bf(a.y); oa.z = f2bf(a.z); oa.w = f2bf(a.w);
        ob.x = f2bf(b.x); ob.y = f2bf(b.y); ob.z = f2bf(b.z); ob.w = f2bf(b.w);
        d[Rg * 1024 + c] = oa;
        d[(Rg + 16) * 1024 + c] = ob;
    }
}

#define GLOBAL_TO_LDS(gp, lp)                                                  \
    __builtin_amdgcn_global_load_lds(                                          \
        (__attribute__((address_space(1))) const void*)(gp),                   \
        (__attribute__((address_space(3))) void*)(lp), 16, 0, 0)

#define BAR() __builtin_amdgcn_s_barrier()
#define SCHEDB() __builtin_amdgcn_sched_barrier(0)
#define LGKM0() do { asm volatile("s_waitcnt lgkmcnt(0)" ::: "memory"); SCHEDB(); } while (0)
#define VMW(n) asm volatile("s_waitcnt vmcnt(" #n ")" ::: "memory")

// bijective XCD-aware block remap (m204). gridDim.x == 16 always here.
__device__ __forceinline__ void remap_block(int gy, int& bx, int& by) {
    int nwg = gy << 4;
    int orig = blockIdx.y * 16 + blockIdx.x;
    int q = nwg >> 3, r = nwg & 7;
    int xcd = orig & 7, lid = orig >> 3;
    int wg = (xcd < r ? xcd * (q + 1) : r * (q + 1) + (xcd - r) * q) + lid;
    bx = wg & 15;
    by = wg >> 4;
}

// ---------------------------------------------------------------------------
// gemm1: X[4096 x K] @ Wc[2I x K interleaved]^T, SwiGLU epilogue -> inter bf16
// 256(M) x 256(combined N) tile, 8 waves (2M x 4N), BK=32, 4-buffer pipeline.
// ---------------------------------------------------------------------------
__global__ __launch_bounds__(512, 2)
void gemm1_swiglu(const unsigned short* __restrict__ Xb,
                  const unsigned short* __restrict__ Wc,
                  unsigned short* __restrict__ inter,
                  const float* __restrict__ gs_p,
                  const float* __restrict__ us_p,
                  int K, int I, int n0, int gy) {
    extern __shared__ unsigned short lds[];   // [0..32767]=A bufs, [32768..65535]=B bufs

    int bx, by;
    remap_block(gy, bx, by);

    const int t = threadIdx.x;
    const int lane = t & 63;
    const int wid = t >> 6;
    const int wm = (wid >> 2) * 128;          // wave M offset (0,128)
    const int wn = (wid & 3) * 64;            // wave combined-N offset (0..192)
    const int fr = lane & 15;
    const int ca = (((lane >> 4) ^ ((fr >> 1) & 3)) << 3);

    const int m_base = bx * 256;
    const long b_row0 = (long)by * 256;

    // staging source pointers (pre-swizzled column so LDS lands linear)
    const int colsw = (((t & 3) ^ ((t >> 3) & 3)) << 3);
    const unsigned short* pa0 = Xb + (size_t)(m_base + (t >> 2)) * K + colsw;
    const unsigned short* pa1 = pa0 + (size_t)128 * K;
    const unsigned short* pb0 = Wc + (size_t)(b_row0 + (t >> 2)) * K + colsw;
    const unsigned short* pb1 = pb0 + (size_t)128 * K;

    f32x4 acc[8][4];
    const f32x4 z = {0.0f, 0.0f, 0.0f, 0.0f};
#pragma unroll
    for (int i = 0; i < 8; ++i)
#pragma unroll
        for (int j = 0; j < 4; ++j) acc[i][j] = z;

    const int aoff = (wm + fr) * 32 + ca;
    const int boff = (wn + fr) * 32 + ca;
    const int Kt = K >> 5;

    // prologue: stage K-tiles 0,1,2 into buffers 0,1,2
#pragma unroll
    for (int s = 0; s < 3; ++s) {
        unsigned short* Aq = lds + s * 8192;
        unsigned short* Bq = lds + 32768 + s * 8192;
        GLOBAL_TO_LDS(pa0, Aq + t * 8);
        GLOBAL_TO_LDS(pa1, Aq + 4096 + t * 8);
        GLOBAL_TO_LDS(pb0, Bq + t * 8);
        GLOBAL_TO_LDS(pb1, Bq + 4096 + t * 8);
        pa0 += 32; pa1 += 32; pb0 += 32; pb1 += 32;
    }
    VMW(8);   // K-tile 0 landed; tiles 1,2 still in flight
    BAR();

    auto KT = [&](int q, int pq, bool pf) {
        unsigned short* Aq = lds + q * 8192;
        unsigned short* Bq = lds + 32768 + q * 8192;
        unsigned short* Ap = lds + pq * 8192;
        unsigned short* Bp = lds + 32768 + pq * 8192;
        short8 af[4], bf[4];
        // ---- phase 1: A rows 0..63 of wave-half + all B frags ----
#pragma unroll
        for (int i = 0; i < 4; ++i)
            af[i] = *(const short8*)(Aq + aoff + i * 512);
#pragma unroll
        for (int n = 0; n < 4; ++n)
            bf[n] = *(const short8*)(Bq + boff + n * 512);
        if (pf) {
            GLOBAL_TO_LDS(pa0, Ap + t * 8);
            GLOBAL_TO_LDS(pa1, Ap + 4096 + t * 8);
        }
        SCHEDB(); BAR(); LGKM0();
        __builtin_amdgcn_s_setprio(1);
#pragma unroll
        for (int mi = 0; mi < 4; ++mi)
#pragma unroll
            for (int ni = 0; ni < 4; ++ni)
                acc[mi][ni] = __builtin_amdgcn_mfma_f32_16x16x32_bf16(
                    af[mi], bf[ni], acc[mi][ni], 0, 0, 0);
        __builtin_amdgcn_s_setprio(0);
        SCHEDB(); BAR();
        // ---- phase 2: A rows 64..127 of wave-half, reuse B frags ----
#pragma unroll
        for (int i = 0; i < 4; ++i)
            af[i] = *(const short8*)(Aq + aoff + (4 + i) * 512);
        if (pf) {
            GLOBAL_TO_LDS(pb0, Bp + t * 8);
            GLOBAL_TO_LDS(pb1, Bp + 4096 + t * 8);
            pa0 += 32; pa1 += 32; pb0 += 32; pb1 += 32;
        }
        SCHEDB(); BAR(); LGKM0();
        __builtin_amdgcn_s_setprio(1);
#pragma unroll
        for (int mi = 0; mi < 4; ++mi)
#pragma unroll
            for (int ni = 0; ni < 4; ++ni)
                acc[4 + mi][ni] = __builtin_amdgcn_mfma_f32_16x16x32_bf16(
                    af[mi], bf[ni], acc[4 + mi][ni], 0, 0, 0);
        __builtin_amdgcn_s_setprio(0);
    };

    int kt = 0;
    for (; kt < Kt - 3; ++kt) {
        KT(kt & 3, (kt + 3) & 3, true);
        VMW(8);   // tile kt+1 landed; kt+2,kt+3 in flight
        BAR();
    }
    KT(kt & 3, 0, false); VMW(4); BAR(); ++kt;   // tile Kt-2 landed
    KT(kt & 3, 0, false); VMW(0); BAR(); ++kt;   // tile Kt-1 landed
    KT(kt & 3, 0, false);                        // last tile, nothing pending

    // ---- SwiGLU epilogue: even frag = gate, odd frag = up ----
    const float gsc = *gs_p;
    const float usc = *us_p;
    const int row0 = m_base + wm + ((lane >> 4) << 2);
    const int col0 = n0 + by * 128 + (wn >> 1) + fr;
#pragma unroll
    for (int mi = 0; mi < 8; ++mi)
#pragma unroll
        for (int p = 0; p < 2; ++p)
#pragma unroll
            for (int r = 0; r < 4; ++r) {
                float g = acc[mi][2 * p][r] * gsc;
                float u = acc[mi][2 * p + 1][r] * usc;
                float s = g / (1.0f + __expf(-g));   // silu
                inter[(size_t)(row0 + mi * 16 + r) * I + (col0 + p * 16)] =
                    f2bf(s * u);
            }
}

// ---------------------------------------------------------------------------
// gemm2: inter[4096 x I] @ Dw[H x I]^T * ds -> out f32. Same pipeline.
// ---------------------------------------------------------------------------
__global__ __launch_bounds__(512, 2)
void gemm2_down(const unsigned short* __restrict__ Ab,
                const unsigned short* __restrict__ Dw,
                float* __restrict__ out,
                const float* __restrict__ ds_p,
                int K, int H, int h0, int gy) {
    extern __shared__ unsigned short lds[];

    int bx, by;
    remap_block(gy, bx, by);

    const int t = threadIdx.x;
    const int lane = t & 63;
    const int wid = t >> 6;
    const int wm = (wid >> 2) * 128;
    const int wn = (wid & 3) * 64;
    const int fr = lane & 15;
    const int ca = (((lane >> 4) ^ ((fr >> 1) & 3)) << 3);

    const int m_base = bx * 256;
    const long b_row0 = (long)by * 256;

    const int colsw = (((t & 3) ^ ((t >> 3) & 3)) << 3);
    const unsigned short* pa0 = Ab + (size_t)(m_base + (t >> 2)) * K + colsw;
    const unsigned short* pa1 = pa0 + (size_t)128 * K;
    const unsigned short* pb0 = Dw + (size_t)(b_row0 + (t >> 2)) * K + colsw;
    const unsigned short* pb1 = pb0 + (size_t)128 * K;

    f32x4 acc[8][4];
    const f32x4 z = {0.0f, 0.0f, 0.0f, 0.0f};
#pragma unroll
    for (int i = 0; i < 8; ++i)
#pragma unroll
        for (int j = 0; j < 4; ++j) acc[i][j] = z;

    const int aoff = (wm + fr) * 32 + ca;
    const int boff = (wn + fr) * 32 + ca;
    const int Kt = K >> 5;   // 11008/32 = 344

#pragma unroll
    for (int s = 0; s < 3; ++s) {
        unsigned short* Aq = lds + s * 8192;
        unsigned short* Bq = lds + 32768 + s * 8192;
        GLOBAL_TO_LDS(pa0, Aq + t * 8);
        GLOBAL_TO_LDS(pa1, Aq + 4096 + t * 8);
        GLOBAL_TO_LDS(pb0, Bq + t * 8);
        GLOBAL_TO_LDS(pb1, Bq + 4096 + t * 8);
        pa0 += 32; pa1 += 32; pb0 += 32; pb1 += 32;
    }
    VMW(8);
    BAR();

    auto KT = [&](int q, int pq, bool pf) {
        unsigned short* Aq = lds + q * 8192;
        unsigned short* Bq = lds + 32768 + q * 8192;
        unsigned short* Ap = lds + pq * 8192;
        unsigned short* Bp = lds + 32768 + pq * 8192;
        short8 af[4], bf[4];
#pragma unroll
        for (int i = 0; i < 4; ++i)
            af[i] = *(const short8*)(Aq + aoff + i * 512);
#pragma unroll
        for (int n = 0; n < 4; ++n)
            bf[n] = *(const short8*)(Bq + boff + n * 512);
        if (pf) {
            GLOBAL_TO_LDS(pa0, Ap + t * 8);
            GLOBAL_TO_LDS(pa1, Ap + 4096 + t * 8);
        }
        SCHEDB(); BAR(); LGKM0();
        __builtin_amdgcn_s_setprio(1);
#pragma unroll
        for (int mi = 0; mi < 4; ++mi)
#pragma unroll
            for (int ni = 0; ni < 4; ++ni)
                acc[mi][ni] = __builtin_amdgcn_mfma_f32_16x16x32_bf16(
                    af[mi], bf[ni], acc[mi][ni], 0, 0, 0);
        __builtin_amdgcn_s_setprio(0);
        SCHEDB(); BAR();
#pragma unroll
        for (int i = 0; i < 4; ++i)
            af[i] = *(const short8*)(Aq + aoff + (4 + i) * 512);
        if (pf) {
            GLOBAL_TO_LDS(pb0, Bp + t * 8);
            GLOBAL_TO_LDS(pb1, Bp + 4096 + t * 8);
            pa0 += 32; pa1 += 32; pb0 += 32; pb1 += 32;
        }
        SCHEDB(); BAR(); LGKM0();
        __builtin_amdgcn_s_setprio(1);
#pragma unroll
        for (int mi = 0; mi < 4; ++mi)
#pragma unroll
            for (int ni = 0; ni < 4; ++ni)
                acc[4 + mi][ni] = __builtin_amdgcn_mfma_f32_16x16x32_bf16(
                    af[mi], bf[ni], acc[4 + mi][ni], 0, 0, 0);
        __builtin_amdgcn_s_setprio(0);
    };

    int kt = 0;
    for (; kt < Kt - 3; ++kt) {
        KT(kt & 3, (kt + 3) & 3, true);
        VMW(8);
        BAR();
    }
    KT(kt & 3, 0, false); VMW(4); BAR(); ++kt;
    KT(kt & 3, 0, false); VMW(0); BAR(); ++kt;
    KT(kt & 3, 0, false);

    const float dsc = *ds_p;
    const int row0 = m_base + wm + ((lane >> 4) << 2);
    const int col0 = h0 + by * 256 + wn + fr;
#pragma unroll
    for (int mi = 0; mi < 8; ++mi)
#pragma unroll
        for (int ni = 0; ni < 4; ++ni)
#pragma unroll
            for (int r = 0; r < 4; ++r)
                out[(size_t)(row0 + mi * 16 + r) * H + (col0 + ni * 16)] =
                    acc[mi][ni][r] * dsc;
}

extern "C" void kernel_launch(void* const* d_in, const int* in_sizes, int n_in,
                              void* d_out, int out_size, void* d_ws, size_t ws_size,
                              hipStream_t stream) {
    (void)in_sizes; (void)n_in; (void)out_size;
    const float* x  = (const float*)d_in[0];
    const float* gw = (const float*)d_in[1];
    const float* uw = (const float*)d_in[2];
    const float* dw = (const float*)d_in[3];
    const float* gs = (const float*)d_in[4];
    const float* us = (const float*)d_in[5];
    const float* ds = (const float*)d_in[6];
    float* out = (float*)d_out;

    const long M = 4096;    // BATCH*SEQ
    const long Kh = 4096;   // HIDDEN
    const long I = 11008;   // INTER
    const long H = 4096;

    // allow 128 KiB dynamic LDS (idempotent; not a stream op, capture-safe)
    (void)hipFuncSetAttribute(reinterpret_cast<const void*>(gemm1_swiglu),
                              hipFuncAttributeMaxDynamicSharedMemorySize, 131072);
    (void)hipFuncSetAttribute(reinterpret_cast<const void*>(gemm2_down),
                              hipFuncAttributeMaxDynamicSharedMemorySize, 131072);

    char* ws = (char*)d_ws;
    unsigned short* Xb = (unsigned short*)ws;                       // M*Kh bf16
    unsigned short* inter = (unsigned short*)(ws + M * Kh * 2);     // M*I bf16
    const size_t used = (size_t)M * Kh * 2 + (size_t)M * I * 2;     // ~124 MB
    if (ws_size < used + 2 * (size_t)256 * I * 2) return;
    char* wbuf = ws + used;
    const size_t avail = ws_size - used;

    // ---- x -> bf16 ----
    {
        long n4 = M * Kh / 4;
        cvt_f32_bf16<<<dim3((unsigned)((n4 + 255) / 256)), dim3(256), 0, stream>>>(
            (const fvec4*)x, (usvec4*)Xb, n4);
    }

    // ---- phase 1: interleaved gate/up convert + fused GEMM1 ----
    long mr1 = (long)(avail / ((size_t)2 * Kh * 2));   // inter cols per chunk
    mr1 = (mr1 / 128) * 128;
    if (mr1 > I) mr1 = I;
    if (mr1 < 128) mr1 = 128;
    unsigned short* Wc = (unsigned short*)wbuf;        // 2*mr1 x Kh interleaved
    for (long n0 = 0; n0 < I; n0 += mr1) {
        long rc = (I - n0 < mr1) ? (I - n0) : mr1;
        long e4 = rc * Kh / 4;
        unsigned cb = (unsigned)((e4 + 255) / 256);
        cvt2_f32_bf16_ilv<<<dim3(cb), dim3(256), 0, stream>>>(
            (const fvec4*)(gw + n0 * Kh), (const fvec4*)(uw + n0 * Kh),
            (usvec4*)Wc, e4);
        unsigned gy = (unsigned)(rc / 128);   // combined-N tiles of 256
        gemm1_swiglu<<<dim3(16, gy), dim3(512), 131072, stream>>>(
            Xb, Wc, inter, gs, us, (int)Kh, (int)I, (int)n0, (int)gy);
    }

    // ---- phase 2: down convert + GEMM2 ----
    long mr2 = (long)(avail / ((size_t)I * 2));
    mr2 = (mr2 / 256) * 256;
    if (mr2 > H) mr2 = H;
    if (mr2 < 256) mr2 = 256;
    unsigned short* Wd = (unsigned short*)wbuf;
    for (long h0 = 0; h0 < H; h0 += mr2) {
        long rc = (H - h0 < mr2) ? (H - h0) : mr2;
        long e4 = rc * I / 4;
        unsigned cb = (unsigned)((e4 + 255) / 256);
        cvt_f32_bf16<<<dim3(cb), dim3(256), 0, stream>>>(
            (const fvec4*)(dw + h0 * I), (usvec4*)Wd, e4);
        unsigned gy = (unsigned)(rc / 256);
        gemm2_down<<<dim3(16, gy), dim3(512), 131072, stream>>>(
            inter, Wd, out, ds, (int)I, (int)H, (int)h0, (int)gy);
    }
}